// Round 2
// baseline (7923.795 us; speedup 1.0000x reference)
//
#include <hip/hip_runtime.h>
#include <hip/hip_bf16.h>
#include <stdint.h>

// P_TNCN: seq=512, batch=128, states=512, out=256, inv_tau=0.5,
// alpha=0.01, beta=0.5.  All tensors are float32 (bf16-grid values).
//
// Per step (per batch row b, independent across b):
//   h_prior = 0.5*h + 0.5*(tanh(h) @ w_r^T + b_r)          [w_i term == 0]
//   x_pred  = tanh(h_prior) @ w_o^T + b_o
//   error   = x_pred - x_t                                   (output)
//   h_post  = h_prior - 0.01*sign(h_prior) - 0.5*(error @ w_f^T)
//
// R2: float32 I/O (R1's NaN == reading f32 storage as bf16). Weights packed
// to bf16 quads (lossless: inputs are bf16-rounded) in workspace; hot loops
// are 8B coalesced weight loads + broadcast ds_read_b128 + 4 FMA per quad.

#define SEQ   512
#define BATCH 128
#define SD    512
#define OD    256

__device__ __forceinline__ float bflo(uint32_t u) { return __uint_as_float(u << 16); }
__device__ __forceinline__ float bfhi(uint32_t u) { return __uint_as_float(u & 0xffff0000u); }

__device__ __forceinline__ uint32_t f32_to_bf16u(float f) {
    uint32_t u = __float_as_uint(f);
    return (u + 0x7fffu + ((u >> 16) & 1u)) >> 16;   // RTNE
}
__device__ __forceinline__ uint32_t pack_bf2(float a, float b) {
    return f32_to_bf16u(a) | (f32_to_bf16u(b) << 16);
}

__device__ __forceinline__ float tanh_fast(float x) {
    float e = __expf(2.0f * x);
    return 1.0f - 2.0f / (e + 1.0f);
}

// ---------------------------------------------------------------------------
// Pack kernel: transposed, 4-k-packed bf16 weight images in workspace.
//   A2 uint2 [128][512] : A2[kq][s] = w_r[s][4kq..4kq+3]     (512 KB)
//   O2 uint2 [ 64][256] : O2[kq][o] = w_o[o][4kq..4kq+3]     (128 KB)
//   F2 uint2 [ 64][512] : F2[oq][s] = w_f[s][4oq..4oq+3]     (256 KB)
// total 896 KB of workspace.
// ---------------------------------------------------------------------------
__global__ void pack_weights(const float* __restrict__ w_o,
                             const float* __restrict__ w_r,
                             const float* __restrict__ w_f,
                             uint2* __restrict__ ws)
{
    const int nA = 128 * 512;           // 65536 uint2
    const int nO = 64 * 256;            // 16384
    const int nF = 64 * 512;            // 32768
    int i = blockIdx.x * 256 + threadIdx.x;
    if (i < nA) {
        int kq = i >> 9, s = i & 511;
        const float* p = &w_r[s * 512 + 4 * kq];
        ws[i] = make_uint2(pack_bf2(p[0], p[1]), pack_bf2(p[2], p[3]));
    } else if (i < nA + nO) {
        int j = i - nA;
        int kq = j >> 8, o = j & 255;
        const float* p = &w_o[o * 512 + 4 * kq];
        ws[i] = make_uint2(pack_bf2(p[0], p[1]), pack_bf2(p[2], p[3]));
    } else if (i < nA + nO + nF) {
        int j = i - nA - nO;
        int oq = j >> 9, s = j & 511;
        const float* p = &w_f[s * 256 + 4 * oq];
        ws[i] = make_uint2(pack_bf2(p[0], p[1]), pack_bf2(p[2], p[3]));
    }
}

// ---------------------------------------------------------------------------
// Main sequential scan: one block per batch row, h state in registers (s=tid).
// ---------------------------------------------------------------------------
__global__ __launch_bounds__(512)
void tncn_scan(const float* __restrict__ x,       // [512][128][256]
               const float* __restrict__ h_init,  // [128][512]
               const float* __restrict__ b_o,     // [256]
               const float* __restrict__ b_r,     // [512]
               const uint2* __restrict__ wsv,
               float* __restrict__ out)           // [512][128][256]
{
    const uint2* A2 = wsv;                  // [128][512]
    const uint2* O2 = wsv + 128 * 512;      // [64][256]
    const uint2* F2 = O2 + 64 * 256;        // [64][512]

    __shared__ float thA[512];   // tanh(h_post) from previous step
    __shared__ float thB[512];   // tanh(h_prior) this step
    __shared__ float er[256];    // error vector this step
    __shared__ float part[512];  // partial sums for x_pred

    const int b   = blockIdx.x;
    const int tid = threadIdx.x;
    const int o   = tid & 255;
    const int kh  = tid >> 8;    // 0/1: k-half for phase B

    const float brf = b_r[tid];
    const float bof = (tid < 256) ? b_o[tid] : 0.0f;

    float hpost = h_init[b * SD + tid];
    thA[tid] = tanh_fast(hpost);
    __syncthreads();

    for (int t = 0; t < SEQ; ++t) {
        // ---- Phase A: h_prior[s=tid] = 0.5*h + 0.5*(tanh(h)@w_r^T + b_r)
        float acc = 0.0f;
        #pragma unroll 8
        for (int kq = 0; kq < 128; ++kq) {
            uint2  u  = A2[kq * 512 + tid];
            float4 tt = *(const float4*)&thA[4 * kq];
            acc += tt.x * bflo(u.x);
            acc += tt.y * bfhi(u.x);
            acc += tt.z * bflo(u.y);
            acc += tt.w * bfhi(u.y);
        }
        float hp = 0.5f * hpost + 0.5f * (acc + brf);
        thB[tid] = tanh_fast(hp);
        __syncthreads();

        // ---- Phase B: x_pred[o] = tanh(h_prior)@w_o^T + b_o ; error = x_pred - x_t
        float accB = 0.0f;
        {
            const int kq0 = kh * 64;
            #pragma unroll 8
            for (int kq = kq0; kq < kq0 + 64; ++kq) {
                uint2  u  = O2[kq * 256 + o];
                float4 tt = *(const float4*)&thB[4 * kq];
                accB += tt.x * bflo(u.x);
                accB += tt.y * bfhi(u.x);
                accB += tt.z * bflo(u.y);
                accB += tt.w * bfhi(u.y);
            }
        }
        part[tid] = accB;
        __syncthreads();
        if (tid < 256) {
            float xp = part[tid] + part[tid + 256] + bof;
            float xv = x[(t * BATCH + b) * OD + tid];
            float e  = xp - xv;
            er[tid]  = e;
            out[(t * BATCH + b) * OD + tid] = e;
        }
        __syncthreads();

        // ---- Phase C: h_post[s=tid] = h_prior - 0.01*sign(h_prior) - 0.5*(er@w_f^T)
        float accC = 0.0f;
        #pragma unroll 8
        for (int oq = 0; oq < 64; ++oq) {
            uint2  u  = F2[oq * 512 + tid];
            float4 ee = *(const float4*)&er[4 * oq];
            accC += ee.x * bflo(u.x);
            accC += ee.y * bfhi(u.x);
            accC += ee.z * bflo(u.y);
            accC += ee.w * bfhi(u.y);
        }
        float sg = (hp > 0.0f) ? 1.0f : ((hp < 0.0f) ? -1.0f : 0.0f);
        hpost = hp - 0.01f * sg - 0.5f * accC;
        thA[tid] = tanh_fast(hpost);
        __syncthreads();
    }
}

extern "C" void kernel_launch(void* const* d_in, const int* in_sizes, int n_in,
                              void* d_out, int out_size, void* d_ws, size_t ws_size,
                              hipStream_t stream)
{
    // setup_inputs order: x, h_init, w_o, b_o, w_r, b_r, w_f, w_i
    const float* x  = (const float*)d_in[0];
    const float* h0 = (const float*)d_in[1];
    const float* wo = (const float*)d_in[2];
    const float* bo = (const float*)d_in[3];
    const float* wr = (const float*)d_in[4];
    const float* br = (const float*)d_in[5];
    const float* wf = (const float*)d_in[6];
    // d_in[7] (w_i) multiplies a zeros tensor in the reference — unused.

    uint2* ws = (uint2*)d_ws;
    float* out = (float*)d_out;

    const int total_pack = 128 * 512 + 64 * 256 + 64 * 512;  // 114688 uint2
    pack_weights<<<(total_pack + 255) / 256, 256, 0, stream>>>(wo, wr, wf, ws);
    tncn_scan<<<BATCH, 512, 0, stream>>>(x, h0, bo, br, ws, out);
}